// Round 5
// baseline (102.401 us; speedup 1.0000x reference)
//
#include <hip/hip_runtime.h>

constexpr int BB = 16;        // batch
constexpr int HH = 512;
constexpr int WW = 512;
constexpr int HW = HH * WW;   // 262144 = 2^18
constexpr int NP1 = BB * HW;  // one single-channel plane: 4,194,304 floats

// 11-tap Gaussian, theta=1, normalized (== normal pdf values to ~1e-8 rel).
__device__ constexpr float GK[11] = {
    1.4867195147342977e-06f,
    1.3383022576488537e-04f,
    4.4318484119380075e-03f,
    5.3990966513188063e-02f,
    2.4197072451914337e-01f,
    3.9894228040143270e-01f,
    2.4197072451914337e-01f,
    5.3990966513188063e-02f,
    4.4318484119380075e-03f,
    1.3383022576488537e-04f,
    1.4867195147342977e-06f,
};
// prefix sums of the smallest taps: PFX[k] = GK[0]+..+GK[k-1]
__device__ constexpr float PFX[6] = {
    0.0f,
    1.4867195147342977e-06f,
    1.3531694527962e-04f,
    4.5671653572176e-03f,
    5.8558131870406e-02f,
    3.0052885638955e-01f,
};

// blur(ones) separable factor with zero padding: missing taps at each edge
__device__ __forceinline__ float edgeS(int i) {
    float s = 1.f;
    if (i < 5)   s -= PFX[5 - i];
    if (i > 506) s -= PFX[i - 506];
    return s;
}

__device__ __forceinline__ float sig1(float d) {
    // q1 = e^d / (1 + e^d), clamped for overflow safety
    d = fminf(fmaxf(d, -30.f), 30.f);
    float e = __expf(d);
    return e * __builtin_amdgcn_rcpf(1.f + e);
}

// ---------------------------------------------------------------------------
// Kernel 1: 3x3 conv, C_in=3 -> C_out=2, SAME zero-pad.
// 2 output rows x 4 px per thread, grid 2048 x 256 -> 8 blocks/CU.
// Writes u0 plane and du = u1 - u0 plane.
// ---------------------------------------------------------------------------
__global__ __launch_bounds__(256) void conv3x3_du(
    const float* __restrict__ x, const float* __restrict__ w,
    const float* __restrict__ bias, float* __restrict__ u0p,
    float* __restrict__ dup)
{
    int bid = blockIdx.x;
    int sb  = (bid & 7) * 256 + (bid >> 3);   // grid 2048, bijective swizzle
    int t   = sb * 256 + threadIdx.x;         // 524,288 threads
    int b   = t >> 15;                        // 32768 threads / image
    int rem = t & 32767;
    int y0  = (rem >> 7) << 1;                // row pair start 0..510
    int xs  = (rem & 127) << 2;               // 4-px strip

    // weights: uniform address -> scalar loads
    float W[54];
#pragma unroll
    for (int i = 0; i < 13; ++i)
        *(float4*)&W[4 * i] = *(const float4*)(w + 4 * i);
    W[52] = w[52];
    W[53] = w[53];
    float b0 = bias[0], b1 = bias[1];

    float acc0[2][4], acc1[2][4];
#pragma unroll
    for (int r = 0; r < 2; ++r)
#pragma unroll
        for (int j = 0; j < 4; ++j) { acc0[r][j] = b0; acc1[r][j] = b1; }

    const float* xb = x + (size_t)b * 3 * HW;
#pragma unroll
    for (int ci = 0; ci < 3; ++ci) {
        const float* xc = xb + ci * HW;
#pragma unroll
        for (int iy = 0; iy < 4; ++iy) {      // input rows y0-1 .. y0+2
            int yy = y0 - 1 + iy;
            if (yy < 0 || yy >= HH) continue; // uniform
            const float* r = xc + yy * WW;
            float4 c = *(const float4*)(r + xs);
            float l  = (xs > 0)      ? r[xs - 1] : 0.f;
            float rr = (xs < WW - 4) ? r[xs + 4] : 0.f;
            float v[6] = {l, c.x, c.y, c.z, c.w, rr};
#pragma unroll
            for (int orow = 0; orow < 2; ++orow) {
                int kh = iy - orow;
                if (kh < 0 || kh > 2) continue;  // compile-time
                float w00 = W[ci * 9 + kh * 3 + 0];
                float w01 = W[ci * 9 + kh * 3 + 1];
                float w02 = W[ci * 9 + kh * 3 + 2];
                float w10 = W[27 + ci * 9 + kh * 3 + 0];
                float w11 = W[27 + ci * 9 + kh * 3 + 1];
                float w12 = W[27 + ci * 9 + kh * 3 + 2];
#pragma unroll
                for (int j = 0; j < 4; ++j) {
                    acc0[orow][j] = fmaf(w00, v[j],
                                    fmaf(w01, v[j + 1],
                                    fmaf(w02, v[j + 2], acc0[orow][j])));
                    acc1[orow][j] = fmaf(w10, v[j],
                                    fmaf(w11, v[j + 1],
                                    fmaf(w12, v[j + 2], acc1[orow][j])));
                }
            }
        }
    }
#pragma unroll
    for (int orow = 0; orow < 2; ++orow) {
        size_t o = (size_t)b * HW + (size_t)(y0 + orow) * WW + xs;
        *(float4*)(u0p + o) = make_float4(acc0[orow][0], acc0[orow][1],
                                          acc0[orow][2], acc0[orow][3]);
        *(float4*)(dup + o) = make_float4(acc1[orow][0] - acc0[orow][0],
                                          acc1[orow][1] - acc0[orow][1],
                                          acc1[orow][2] - acc0[orow][2],
                                          acc1[orow][3] - acc0[orow][3]);
    }
}

// ---------------------------------------------------------------------------
// Kernel 2: one CRF iteration on the channel-difference state.
//   m1 = blur(sigmoid(d));  d' = du + 2*m1 - Sx*Sy
// MODE 0: dcur == du (first iteration); reuses in-flight du rows
// MODE 1: middle iteration
// MODE 2: final: out0 = u0 + SxSy - m1 ; out1 = u0 + du + m1  (NCHW out)
// 4 output rows per block; 256 threads: half-block g owns rows {2g, 2g+1}.
// Grid 2048 -> 8 blocks/CU -> 32 waves/CU.
// ---------------------------------------------------------------------------
template <int MODE>
__global__ __launch_bounds__(256) void crf_diff(
    const float* __restrict__ dcur, const float* __restrict__ dup,
    const float* __restrict__ u0p, float* __restrict__ outp)
{
    __shared__ float v[4][528];

    int bid  = blockIdx.x;
    int tile = (bid & 7) * 256 + (bid >> 3);   // grid 2048, bijective
    int b    = tile >> 7;                      // 128 tiles / image
    int y0   = (tile & 127) << 2;              // 4 output rows
    int tid  = threadIdx.x;
    int g    = tid >> 7;                       // 0/1 -> rows {0,1} / {2,3}
    int x0   = (tid & 127) << 2;
    int r0   = y0 + 2 * g;

    if (tid < 5) {
#pragma unroll
        for (int r = 0; r < 4; ++r) {
            v[r][3 + tid] = 0.f;
            v[r][520 + tid] = 0.f;
        }
    }

    const float* dbase = dcur + (size_t)b * HW + x0;

    float acc[2][4] = {{0.f}};
    float4 raw[2];                             // du rows for MODE0 epilogue
    raw[0] = make_float4(0.f, 0.f, 0.f, 0.f);
    raw[1] = raw[0];
#pragma unroll
    for (int i = 0; i < 12; ++i) {             // input rows r0-5 .. r0+6
        int yy = r0 + i - 5;
        if (yy < 0 || yy >= HH) continue;      // uniform within wave
        float4 dv = *(const float4*)(dbase + yy * WW);
        if (MODE == 0) {
            if (i == 5) raw[0] = dv;           // dv == du at output row r0
            if (i == 6) raw[1] = dv;           // and r0+1
        }
        float q[4] = {sig1(dv.x), sig1(dv.y), sig1(dv.z), sig1(dv.w)};
#pragma unroll
        for (int j = 0; j < 2; ++j) {
            int dt = i - j;
            if (dt < 0 || dt > 10) continue;   // compile-time
            float k = GK[dt];
#pragma unroll
            for (int jj = 0; jj < 4; ++jj)
                acc[j][jj] = fmaf(k, q[jj], acc[j][jj]);
        }
    }
#pragma unroll
    for (int j = 0; j < 2; ++j)
        *(float4*)(&v[2 * g + j][8 + x0]) =
            make_float4(acc[j][0], acc[j][1], acc[j][2], acc[j][3]);
    __syncthreads();

    float Sx[4];
#pragma unroll
    for (int j = 0; j < 4; ++j) Sx[j] = edgeS(x0 + j);

#pragma unroll
    for (int j = 0; j < 2; ++j) {
        int lr = 2 * g + j;
        int yy = y0 + lr;
        float Sy = edgeS(yy);

        float4 A = *(const float4*)(&v[lr][x0]);
        float4 Bq = *(const float4*)(&v[lr][x0 + 4]);
        float4 C = *(const float4*)(&v[lr][x0 + 8]);
        float4 D = *(const float4*)(&v[lr][x0 + 12]);
        float4 E = *(const float4*)(&v[lr][x0 + 16]);
        float wv[14] = {A.w, Bq.x, Bq.y, Bq.z, Bq.w, C.x, C.y, C.z, C.w,
                        D.x, D.y, D.z, D.w, E.x};

        float m1[4];
#pragma unroll
        for (int jj = 0; jj < 4; ++jj) {
            float s = 0.f;
#pragma unroll
            for (int t = 0; t < 11; ++t)
                s = fmaf(GK[t], wv[jj + t], s);
            m1[jj] = s;
        }

        size_t po = (size_t)b * HW + (size_t)yy * WW + x0;
        float4 duv;
        if (MODE == 0) duv = raw[j];
        else           duv = *(const float4*)(dup + po);

        if (MODE == 2) {
            float4 u0v = *(const float4*)(u0p + po);
            size_t oo = (size_t)b * 2 * HW + (size_t)yy * WW + x0;
            float o0[4], o1[4];
#pragma unroll
            for (int jj = 0; jj < 4; ++jj) {
                float S = Sx[jj] * Sy;
                float u0s = (&u0v.x)[jj];
                float dus = (&duv.x)[jj];
                o0[jj] = u0s + (S - m1[jj]);
                o1[jj] = (u0s + dus) + m1[jj];
            }
            *(float4*)(outp + oo)      = make_float4(o0[0], o0[1], o0[2], o0[3]);
            *(float4*)(outp + oo + HW) = make_float4(o1[0], o1[1], o1[2], o1[3]);
        } else {
            float dn[4];
#pragma unroll
            for (int jj = 0; jj < 4; ++jj) {
                float S = Sx[jj] * Sy;
                dn[jj] = (&duv.x)[jj] + fmaf(2.f, m1[jj], -S);
            }
            *(float4*)(outp + po) = make_float4(dn[0], dn[1], dn[2], dn[3]);
        }
    }
}

extern "C" void kernel_launch(void* const* d_in, const int* in_sizes, int n_in,
                              void* d_out, int out_size, void* d_ws, size_t ws_size,
                              hipStream_t stream) {
    const float* x    = (const float*)d_in[0];   // (16,3,512,512)
    const float* w    = (const float*)d_in[1];   // (2,3,3,3)
    const float* bias = (const float*)d_in[2];   // (2,)

    float* out = (float*)d_out;                  // (16,2,512,512)
    float* u0p = (float*)d_ws;                   // 16.8 MB
    float* dup = u0p + NP1;                      // 16.8 MB
    float* dA  = dup + NP1;                      // 16.8 MB
    float* dB  = dA + NP1;                       // 16.8 MB

    conv3x3_du<<<2048, 256, 0, stream>>>(x, w, bias, u0p, dup);
    crf_diff<0><<<2048, 256, 0, stream>>>(dup, dup, u0p, dA);   // it0
    crf_diff<1><<<2048, 256, 0, stream>>>(dA,  dup, u0p, dB);   // it1
    crf_diff<1><<<2048, 256, 0, stream>>>(dB,  dup, u0p, dA);   // it2
    crf_diff<1><<<2048, 256, 0, stream>>>(dA,  dup, u0p, dB);   // it3
    crf_diff<2><<<2048, 256, 0, stream>>>(dB,  dup, u0p, out);  // it4 -> out
}

// Round 6
// 94.927 us; speedup vs baseline: 1.0787x; 1.0787x over previous
//
#include <hip/hip_runtime.h>

constexpr int BB = 16;        // batch
constexpr int HH = 512;
constexpr int WW = 512;
constexpr int HW = HH * WW;   // 262144 = 2^18
constexpr int NP1 = BB * HW;  // one single-channel plane: 4,194,304 floats

// 11-tap Gaussian, theta=1, normalized (== normal pdf values to ~1e-8 rel).
__device__ constexpr float GK[11] = {
    1.4867195147342977e-06f,
    1.3383022576488537e-04f,
    4.4318484119380075e-03f,
    5.3990966513188063e-02f,
    2.4197072451914337e-01f,
    3.9894228040143270e-01f,
    2.4197072451914337e-01f,
    5.3990966513188063e-02f,
    4.4318484119380075e-03f,
    1.3383022576488537e-04f,
    1.4867195147342977e-06f,
};
// prefix sums of the smallest taps: PFX[k] = GK[0]+..+GK[k-1]
__device__ constexpr float PFX[6] = {
    0.0f,
    1.4867195147342977e-06f,
    1.3531694527962e-04f,
    4.5671653572176e-03f,
    5.8558131870406e-02f,
    3.0052885638955e-01f,
};

// blur(ones) separable factor with zero padding: missing taps at each edge
__device__ __forceinline__ float edgeS(int i) {
    float s = 1.f;
    if (i < 5)   s -= PFX[5 - i];
    if (i > 506) s -= PFX[i - 506];
    return s;
}

__device__ __forceinline__ float sig1(float d) {
    // q1 = e^d / (1 + e^d), clamped for overflow safety
    d = fminf(fmaxf(d, -30.f), 30.f);
    float e = __expf(d);
    return e * __builtin_amdgcn_rcpf(1.f + e);
}

// ---------------------------------------------------------------------------
// Kernel 1: 3x3 conv, C_in=3 -> C_out=2, SAME zero-pad.  (round-4 version)
// 2 output rows x 8 px per thread; weights hoisted; grid 1024 x 256
// -> 16 waves/CU. Writes u0 plane and du = u1 - u0 plane.
// ---------------------------------------------------------------------------
__global__ __launch_bounds__(256) void conv3x3_du(
    const float* __restrict__ x, const float* __restrict__ w,
    const float* __restrict__ bias, float* __restrict__ u0p,
    float* __restrict__ dup)
{
    int bid = blockIdx.x;
    int sb  = (bid & 7) * 128 + (bid >> 3);     // grid 1024, bijective
    int t   = sb * 256 + threadIdx.x;
    int b   = t >> 14;                          // 16384 threads / image
    int rem = t & 16383;
    int y0  = (rem >> 6) << 1;                  // row pair 0,2,..,510
    int xs  = (rem & 63) << 3;                  // 8-px strip

    float W[54];
#pragma unroll
    for (int i = 0; i < 13; ++i)
        *(float4*)&W[4 * i] = *(const float4*)(w + 4 * i);
    W[52] = w[52];
    W[53] = w[53];
    float b0 = bias[0], b1 = bias[1];

    float acc0[2][8], acc1[2][8];
#pragma unroll
    for (int r = 0; r < 2; ++r)
#pragma unroll
        for (int j = 0; j < 8; ++j) { acc0[r][j] = b0; acc1[r][j] = b1; }

    const float* xb = x + (size_t)b * 3 * HW;
#pragma unroll
    for (int ci = 0; ci < 3; ++ci) {
        const float* xc = xb + ci * HW;
#pragma unroll
        for (int iy = 0; iy < 4; ++iy) {        // input rows y0-1 .. y0+2
            int yy = y0 - 1 + iy;
            if (yy < 0 || yy >= HH) continue;   // uniform
            const float* r = xc + yy * WW;
            float4 cA = *(const float4*)(r + xs);
            float4 cB = *(const float4*)(r + xs + 4);
            float l  = (xs > 0)      ? r[xs - 1] : 0.f;
            float rr = (xs < WW - 8) ? r[xs + 8] : 0.f;
            float v[10] = {l, cA.x, cA.y, cA.z, cA.w,
                           cB.x, cB.y, cB.z, cB.w, rr};
#pragma unroll
            for (int orow = 0; orow < 2; ++orow) {
                int kh = iy - orow;
                if (kh < 0 || kh > 2) continue;  // compile-time
                float w00 = W[ci * 9 + kh * 3 + 0];
                float w01 = W[ci * 9 + kh * 3 + 1];
                float w02 = W[ci * 9 + kh * 3 + 2];
                float w10 = W[27 + ci * 9 + kh * 3 + 0];
                float w11 = W[27 + ci * 9 + kh * 3 + 1];
                float w12 = W[27 + ci * 9 + kh * 3 + 2];
#pragma unroll
                for (int j = 0; j < 8; ++j) {
                    acc0[orow][j] = fmaf(w00, v[j],
                                    fmaf(w01, v[j + 1],
                                    fmaf(w02, v[j + 2], acc0[orow][j])));
                    acc1[orow][j] = fmaf(w10, v[j],
                                    fmaf(w11, v[j + 1],
                                    fmaf(w12, v[j + 2], acc1[orow][j])));
                }
            }
        }
    }
#pragma unroll
    for (int orow = 0; orow < 2; ++orow) {
        size_t o = (size_t)b * HW + (size_t)(y0 + orow) * WW + xs;
        *(float4*)(u0p + o)     = make_float4(acc0[orow][0], acc0[orow][1],
                                              acc0[orow][2], acc0[orow][3]);
        *(float4*)(u0p + o + 4) = make_float4(acc0[orow][4], acc0[orow][5],
                                              acc0[orow][6], acc0[orow][7]);
        *(float4*)(dup + o)     = make_float4(acc1[orow][0] - acc0[orow][0],
                                              acc1[orow][1] - acc0[orow][1],
                                              acc1[orow][2] - acc0[orow][2],
                                              acc1[orow][3] - acc0[orow][3]);
        *(float4*)(dup + o + 4) = make_float4(acc1[orow][4] - acc0[orow][4],
                                              acc1[orow][5] - acc0[orow][5],
                                              acc1[orow][6] - acc0[orow][6],
                                              acc1[orow][7] - acc0[orow][7]);
    }
}

// ---------------------------------------------------------------------------
// Kernel 2: one CRF iteration on the channel-difference state.
//   m = blur(sigmoid(d));  d' = du + 2*m - Sx*Sy
// MODE 0: dcur == du (first iteration); reuses in-flight du rows
// MODE 1: middle iteration
// MODE 2: final: out0 = u0 + SxSy - m ; out1 = u0 + du + m  (NCHW out)
// 8 output rows per block; 256 threads x 2 px cover a full 512-px row.
// Grid 1024 -> 4 blocks/CU x 4 waves = 16 waves/CU; halo amp 18/8 = 2.25x.
// LDS rows: zeros [0,5), data at [5+x], zeros [517,522); hblur window for
// px pair at x0 is floats [x0, x0+11] -> 6 aligned float2 reads.
// ---------------------------------------------------------------------------
template <int MODE>
__global__ __launch_bounds__(256) void crf_diff2(
    const float* __restrict__ dcur, const float* __restrict__ dup,
    const float* __restrict__ u0p, float* __restrict__ outp)
{
    __shared__ float v[8][528];

    int bid  = blockIdx.x;
    int tile = (bid & 7) * 128 + (bid >> 3);   // grid 1024, bijective
    int b    = tile >> 6;                      // 64 tiles / image
    int y0   = (tile & 63) << 3;               // 8 output rows
    int tid  = threadIdx.x;
    int x0   = tid << 1;                       // 2 px per thread

    if (tid < 5) {
#pragma unroll
        for (int r = 0; r < 8; ++r) {
            v[r][tid] = 0.f;
            v[r][517 + tid] = 0.f;
        }
    }

    const float* dbase = dcur + (size_t)b * HW + x0;

    float acc[8][2] = {{0.f}};
    float2 raw[8];                             // du rows for MODE0 epilogue
#pragma unroll
    for (int i = 0; i < 18; ++i) {             // input rows y0-5 .. y0+12
        int yy = y0 + i - 5;
        if (yy < 0 || yy >= HH) continue;      // uniform
        float2 dv = *(const float2*)(dbase + yy * WW);
        if (MODE == 0) {
            if (i >= 5 && i <= 12) raw[i - 5] = dv;  // du at output rows
        }
        float qa = sig1(dv.x), qb = sig1(dv.y);
#pragma unroll
        for (int r = 0; r < 8; ++r) {
            int dt = i - r;
            if (dt < 0 || dt > 10) continue;   // compile-time
            float k = GK[dt];
            acc[r][0] = fmaf(k, qa, acc[r][0]);
            acc[r][1] = fmaf(k, qb, acc[r][1]);
        }
    }
#pragma unroll
    for (int r = 0; r < 8; ++r)
        *(float2*)(&v[r][5 + x0]) = make_float2(acc[r][0], acc[r][1]);
    __syncthreads();

    float SxA = edgeS(x0), SxB = edgeS(x0 + 1);

#pragma unroll
    for (int r = 0; r < 8; ++r) {
        int yy = y0 + r;
        float Sy = edgeS(yy);

        float wv[12];
#pragma unroll
        for (int t = 0; t < 6; ++t)
            *(float2*)&wv[2 * t] = *(const float2*)(&v[r][x0 + 2 * t]);

        float m0 = 0.f, m1 = 0.f;
#pragma unroll
        for (int t = 0; t < 11; ++t) {
            m0 = fmaf(GK[t], wv[t], m0);
            m1 = fmaf(GK[t], wv[t + 1], m1);
        }

        size_t po = (size_t)b * HW + (size_t)yy * WW + x0;
        float2 duv;
        if (MODE == 0) duv = raw[r];
        else           duv = *(const float2*)(dup + po);

        float S0 = SxA * Sy, S1 = SxB * Sy;
        if (MODE == 2) {
            float2 u0v = *(const float2*)(u0p + po);
            size_t oo = (size_t)b * 2 * HW + (size_t)yy * WW + x0;
            *(float2*)(outp + oo)      = make_float2(u0v.x + (S0 - m0),
                                                     u0v.y + (S1 - m1));
            *(float2*)(outp + oo + HW) = make_float2((u0v.x + duv.x) + m0,
                                                     (u0v.y + duv.y) + m1);
        } else {
            *(float2*)(outp + po) = make_float2(duv.x + fmaf(2.f, m0, -S0),
                                                duv.y + fmaf(2.f, m1, -S1));
        }
    }
}

extern "C" void kernel_launch(void* const* d_in, const int* in_sizes, int n_in,
                              void* d_out, int out_size, void* d_ws, size_t ws_size,
                              hipStream_t stream) {
    const float* x    = (const float*)d_in[0];   // (16,3,512,512)
    const float* w    = (const float*)d_in[1];   // (2,3,3,3)
    const float* bias = (const float*)d_in[2];   // (2,)

    float* out = (float*)d_out;                  // (16,2,512,512)
    float* u0p = (float*)d_ws;                   // 16.8 MB
    float* dup = u0p + NP1;                      // 16.8 MB
    float* dA  = dup + NP1;                      // 16.8 MB
    float* dB  = dA + NP1;                       // 16.8 MB

    conv3x3_du<<<1024, 256, 0, stream>>>(x, w, bias, u0p, dup);
    crf_diff2<0><<<1024, 256, 0, stream>>>(dup, dup, u0p, dA);   // it0
    crf_diff2<1><<<1024, 256, 0, stream>>>(dA,  dup, u0p, dB);   // it1
    crf_diff2<1><<<1024, 256, 0, stream>>>(dB,  dup, u0p, dA);   // it2
    crf_diff2<1><<<1024, 256, 0, stream>>>(dA,  dup, u0p, dB);   // it3
    crf_diff2<2><<<1024, 256, 0, stream>>>(dB,  dup, u0p, out);  // it4 -> out
}